// Round 2
// baseline (432.449 us; speedup 1.0000x reference)
//
#include <hip/hip_runtime.h>
#include <hip/hip_bf16.h>
#include <math.h>

// Problem constants
#define B_  8
#define C_  64
#define H_  256
#define W_  256
#define HW_ (H_*W_)
#define J_  192          // 3*C intermediate channels

typedef __attribute__((ext_vector_type(8))) short short8;
typedef __attribute__((ext_vector_type(4))) float f32x4;

// ---- bf16 helpers (RNE) ----
__device__ __forceinline__ ushort f2bf(float f) {
    union { float f; uint u; } v; v.f = f;
    uint u = v.u;
    return (ushort)((u + 0x7fffu + ((u >> 16) & 1u)) >> 16);
}
__device__ __forceinline__ float bf2f(ushort s) {
    union { uint u; float f; } v; v.u = ((uint)s) << 16;
    return v.f;
}
__device__ __forceinline__ uint pk(float a, float b) {
    return (uint)f2bf(a) | ((uint)f2bf(b) << 16);
}
// 1-op bf16->f32 unpacks from a packed pair
__device__ __forceinline__ float bflo(uint u) {
    union { uint u; float f; } v; v.u = u << 16; return v.f;
}
__device__ __forceinline__ float bfhi(uint u) {
    union { uint u; float f; } v; v.u = u & 0xffff0000u; return v.f;
}

// ---------------------------------------------------------------------------
// K1: v[b, j, px] = sum_c Wm[j,c] * x[b,c,px]   (bf16 out), via MFMA.
//   Wm[j][c] = fw[(j&63)*192 + (j>>6)*64 + c]   (mix commutes with blur)
// Block = (b, 256-px strip). x-tile staged to LDS transposed [px][c] in bf16,
// 8B granules XOR-swizzled: slot(px, c4) = c4 ^ ((px>>2)&15) ^ ((px&3)<<2).
// MFMA 16x16x32: A = x (m=px, k=c from LDS), B = Wm (n=j, from global regs),
// D: col=lane&15 = j, row=(lane>>4)*4+reg = px -> 4 consecutive px packed 8B.
// [UNCHANGED again — once k2 drops below it, k1 enters rocprof top-5 and we
//  get counters to attack its ~200 us (vs ~55 us HBM roofline) next round]
// ---------------------------------------------------------------------------
__global__ __launch_bounds__(256) void k1_mix(
    const float* __restrict__ x, const float* __restrict__ fw,
    ushort* __restrict__ v)
{
    __shared__ ushort lxs[256 * 64];   // 32 KB

    const int b      = blockIdx.x >> 8;
    const int pxbase = (blockIdx.x & 255) << 8;
    const int t      = threadIdx.x;
    const int lane   = t & 63;
    const int wv_    = t >> 6;

    // ---- stage x [64c x 256px] fp32 -> LDS bf16 transposed ----
    {
        const int cg = lane;            // px-quad group 0..63
        const float* xb = x + (size_t)b * C_ * HW_ + pxbase + 4 * cg;
#pragma unroll
        for (int i = 0; i < 4; ++i) {
            const int cb = wv_ * 4 + i * 16;    // c base (4 consecutive c)
            const int c4 = wv_ + i * 4;         // granule index
            float4 r0 = *(const float4*)(xb + (size_t)(cb + 0) * HW_);
            float4 r1 = *(const float4*)(xb + (size_t)(cb + 1) * HW_);
            float4 r2 = *(const float4*)(xb + (size_t)(cb + 2) * HW_);
            float4 r3 = *(const float4*)(xb + (size_t)(cb + 3) * HW_);
            const int sbase = c4 ^ (cg & 15);
            ushort* dst = &lxs[(4 * cg) * 64];
            *(uint2*)(dst + 0*64 + ((sbase ^ 0) * 4)) = make_uint2(pk(r0.x, r1.x), pk(r2.x, r3.x));
            *(uint2*)(dst + 1*64 + ((sbase ^ 4) * 4)) = make_uint2(pk(r0.y, r1.y), pk(r2.y, r3.y));
            *(uint2*)(dst + 2*64 + ((sbase ^ 8) * 4)) = make_uint2(pk(r0.z, r1.z), pk(r2.z, r3.z));
            *(uint2*)(dst + 3*64 + ((sbase ^ 12) * 4)) = make_uint2(pk(r0.w, r1.w), pk(r2.w, r3.w));
        }
    }

    // ---- W fragments (B operand), 3 j-tiles per wave, kept in regs ----
    const int n = lane & 15;           // j within tile / B-frag col
    const int q = lane >> 4;           // quad
    union Frag { short8 v; uint u[4]; };
    Frag wf[3][2];
#pragma unroll
    for (int i = 0; i < 3; ++i) {
        const int j  = (wv_ * 3 + i) * 16 + n;
        const float* wr = fw + (size_t)(j & 63) * J_ + (j >> 6) * 64;
#pragma unroll
        for (int kh = 0; kh < 2; ++kh) {
            float4 w0 = *(const float4*)(wr + kh * 32 + q * 8);
            float4 w1 = *(const float4*)(wr + kh * 32 + q * 8 + 4);
            wf[i][kh].u[0] = pk(w0.x, w0.y);
            wf[i][kh].u[1] = pk(w0.z, w0.w);
            wf[i][kh].u[2] = pk(w1.x, w1.y);
            wf[i][kh].u[3] = pk(w1.z, w1.w);
        }
    }

    __syncthreads();

    // ---- 16 px-tiles x 3 j-tiles ----
    for (int mt = 0; mt < 16; ++mt) {
        const int px = mt * 16 + (lane & 15);          // A-frag m
        const ushort* row = &lxs[px * 64];
        const int s = ((px >> 2) & 15) ^ ((px & 3) << 2);
        Frag a0, a1;
        {
            uint2 lo  = *(const uint2*)&row[((2*q    ) ^ s) * 4];
            uint2 hi  = *(const uint2*)&row[((2*q + 1) ^ s) * 4];
            a0.u[0] = lo.x;  a0.u[1] = lo.y;  a0.u[2] = hi.x;  a0.u[3] = hi.y;
            uint2 lo1 = *(const uint2*)&row[((8 + 2*q    ) ^ s) * 4];
            uint2 hi1 = *(const uint2*)&row[((8 + 2*q + 1) ^ s) * 4];
            a1.u[0] = lo1.x; a1.u[1] = lo1.y; a1.u[2] = hi1.x; a1.u[3] = hi1.y;
        }
#pragma unroll
        for (int i = 0; i < 3; ++i) {
            f32x4 acc = {0.f, 0.f, 0.f, 0.f};
            acc = __builtin_amdgcn_mfma_f32_16x16x32_bf16(a0.v, wf[i][0].v, acc, 0, 0, 0);
            acc = __builtin_amdgcn_mfma_f32_16x16x32_bf16(a1.v, wf[i][1].v, acc, 0, 0, 0);
            const int j   = (wv_ * 3 + i) * 16 + n;
            const int pxg = pxbase + mt * 16 + q * 4;  // D row = q*4 + reg
            *(uint2*)&v[(size_t)(b * J_ + j) * HW_ + pxg] =
                make_uint2(pk(acc[0], acc[1]), pk(acc[2], acc[3]));
        }
    }
}

// ---------------------------------------------------------------------------
// K2 (v3): out[b,o] = x[b,o] + bias[o] + sum_s vblur_s(hblur_s(v[b, s*64+o]))
//
// Block = (b, o, 16-row x 256-col tile). ONE barrier.
// Phase 1: block computes every hblur row for ALL scales exactly once into
//   LDS (70 rows x 256 cols bf16 = 35 KB): s0 rows [0,20), s1 [20,42),
//   s2 [42,70). Each v row is fetched once per block (vs 3-5x horizontal and
//   1.5-2.5x vertical re-reads in v2) -> ~5x fewer global load instrs/bytes.
// Phase 2: vertical scatter from LDS; per-thread acc is only 4 float4 (16 f32,
//   fixing v2's 60+ live values squeezed into 40 VGPRs -> rematerialization).
// All LDS ops are full-wave contiguous 8B/lane -> conflict-free.
// ---------------------------------------------------------------------------
#define TH2_ 16                    // output tile rows
#define TROWS_ (TH2_+4 + TH2_+6 + TH2_+12)   // 70 tmp rows

struct Taps {
    float g0[5];    // sigma 0.5, r=2
    float g1[7];    // sigma 1.0, r=3
    float g2[13];   // sigma 2.0, r=6
};

// hblur one row (4 cols at granule cg) of one scale -> LDS row
template<int R, int G>
__device__ __forceinline__ void hjob(
    const ushort* __restrict__ vplane, const float* __restrict__ g,
    ushort* __restrict__ dstrow, int gh, int cg)
{
    const int NG  = 2 * G + 1;     // 8B granules loaded
    const int OFF = 4 * G - R;     // window offset (>=0 since R<=4G)
    const int K   = 2 * R + 1;     // taps
    float o0 = 0.f, o1 = 0.f, o2 = 0.f, o3 = 0.f;
    if (gh >= 0 && gh < H_) {
        const ushort* vr = vplane + (size_t)gh * W_;
        float win[NG * 4];
#pragma unroll
        for (int gi = 0; gi < NG; ++gi) {
            const int gg = cg - G + gi;
            uint2 d = (gg >= 0 && gg < 64) ? *(const uint2*)(vr + gg * 4)
                                           : make_uint2(0u, 0u);
            win[gi*4+0] = bflo(d.x); win[gi*4+1] = bfhi(d.x);
            win[gi*4+2] = bflo(d.y); win[gi*4+3] = bfhi(d.y);
        }
#pragma unroll
        for (int dd = 0; dd < K; ++dd) {
            const float gd = g[dd];
            o0 += gd * win[OFF + dd + 0];
            o1 += gd * win[OFF + dd + 1];
            o2 += gd * win[OFF + dd + 2];
            o3 += gd * win[OFF + dd + 3];
        }
    }
    // out-of-range rows write zeros (phase 2 reads unconditionally)
    *(uint2*)&dstrow[4 * cg] = make_uint2(pk(o0, o1), pk(o2, o3));
}

// vertical scatter for one scale: tmp0 points at this thread's first tmp row
template<int R>
__device__ __forceinline__ void vjob(
    const ushort* __restrict__ tmp0, const float* __restrict__ g,
    int cg, float4* acc)
{
#pragma unroll
    for (int k = 0; k < 4 + 2 * R; ++k) {
        uint2 raw = *(const uint2*)&tmp0[k * W_ + 4 * cg];
        const float f0 = bflo(raw.x), f1 = bfhi(raw.x);
        const float f2 = bflo(raw.y), f3 = bfhi(raw.y);
        const int ilo = (k - 2 * R) > 0 ? (k - 2 * R) : 0;
        const int ihi = k < 3 ? k : 3;
#pragma unroll
        for (int i = ilo; i <= ihi; ++i) {
            const float gd = g[k - i];
            acc[i].x += gd * f0;
            acc[i].y += gd * f1;
            acc[i].z += gd * f2;
            acc[i].w += gd * f3;
        }
    }
}

__global__ __launch_bounds__(256, 4) void k2_blur(
    const ushort* __restrict__ v, const float* __restrict__ x,
    const float* __restrict__ bias, float* __restrict__ out,
    Taps taps)
{
    __shared__ ushort tmp[TROWS_ * W_];   // 70*256*2 = 35840 B -> 4 blocks/CU

    const int t    = blockIdx.x;
    const int tile = t & 15;
    const int o    = (t >> 4) & 63;
    const int b    = t >> 10;
    const int h0   = tile * TH2_;
    const int cg   = threadIdx.x & 63;       // col granule (4 cols)
    const int rw   = threadIdx.x >> 6;       // wave id
    const int c0   = cg * 4;

    const ushort* vp = v + (size_t)(b * J_ + o) * HW_;

    // ---- phase 1: all hblur rows, each computed once, into LDS ----
    // (r is wave-uniform in every loop; bodies fully unrolled & branch-free)
    for (int r = rw; r < TH2_ + 4; r += 4)
        hjob<2, 1>(vp,                        taps.g0, &tmp[r * W_],            h0 - 2 + r, cg);
    for (int r = rw; r < TH2_ + 6; r += 4)
        hjob<3, 1>(vp + (size_t)C_ * HW_,     taps.g1, &tmp[(20 + r) * W_],     h0 - 3 + r, cg);
    for (int r = rw; r < TH2_ + 12; r += 4)
        hjob<6, 2>(vp + (size_t)(2*C_) * HW_, taps.g2, &tmp[(42 + r) * W_],     h0 - 6 + r, cg);

    __syncthreads();

    // ---- phase 2: vertical scatter, 4 output rows per thread ----
    float4 acc[4];
#pragma unroll
    for (int i = 0; i < 4; ++i) acc[i] = make_float4(0.f, 0.f, 0.f, 0.f);

    vjob<2>(&tmp[(0  + rw * 4) * W_], taps.g0, cg, acc);
    vjob<3>(&tmp[(20 + rw * 4) * W_], taps.g1, cg, acc);
    vjob<6>(&tmp[(42 + rw * 4) * W_], taps.g2, cg, acc);

    // ---- epilogue: + x + bias ----
    const int row0 = h0 + rw * 4;
    const float* xp = x   + ((size_t)b * C_ + o) * HW_ + (size_t)row0 * W_;
    float*       op = out + ((size_t)b * C_ + o) * HW_ + (size_t)row0 * W_;
    const float bo = bias[o];
#pragma unroll
    for (int i = 0; i < 4; ++i) {
        float4 xv = *(const float4*)&xp[(size_t)i * W_ + c0];
        float4 r;
        r.x = xv.x + bo + acc[i].x;
        r.y = xv.y + bo + acc[i].y;
        r.z = xv.z + bo + acc[i].z;
        r.w = xv.w + bo + acc[i].w;
        *(float4*)&op[(size_t)i * W_ + c0] = r;
    }
}

// ---------------------------------------------------------------------------
static void make_taps(Taps& t)
{
    auto fill = [](float* g, int k, double sigma) {
        int r = k / 2;
        double s = 0.0;
        for (int i = 0; i < k; ++i) {
            double w = exp(-(double)((i - r) * (i - r)) / (2.0 * sigma * sigma));
            g[i] = (float)w;
            s += w;
        }
        for (int i = 0; i < k; ++i) g[i] = (float)((double)g[i] / s);
    };
    fill(t.g0, 5, 0.5);
    fill(t.g1, 7, 1.0);
    fill(t.g2, 13, 2.0);
}

extern "C" void kernel_launch(void* const* d_in, const int* in_sizes, int n_in,
                              void* d_out, int out_size, void* d_ws, size_t ws_size,
                              hipStream_t stream)
{
    const float* x  = (const float*)d_in[0];
    const float* fw = (const float*)d_in[1];
    const float* fb = (const float*)d_in[2];
    float* out = (float*)d_out;
    ushort* v = (ushort*)d_ws;   // bf16 intermediate, 8*192*65536*2 = 201 MB

    Taps taps;
    make_taps(taps);

    k1_mix<<<dim3(B_ * (HW_ / 256)), dim3(256), 0, stream>>>(x, fw, v);
    k2_blur<<<dim3(B_ * C_ * (H_ / TH2_)), dim3(256), 0, stream>>>(v, x, fb, out, taps);
}

// Round 5
// 424.551 us; speedup vs baseline: 1.0186x; 1.0186x over previous
//
#include <hip/hip_runtime.h>
#include <hip/hip_bf16.h>
#include <math.h>

// Problem constants
#define B_  8
#define C_  64
#define H_  256
#define W_  256
#define HW_ (H_*W_)
#define J_  192          // 3*C intermediate channels
#define TH2_ 16          // K2 output tile rows

typedef __attribute__((ext_vector_type(8))) short short8;
typedef __attribute__((ext_vector_type(4))) float f32x4;

// ---- bf16 helpers (RNE) ----
__device__ __forceinline__ ushort f2bf(float f) {
    union { float f; uint u; } v; v.f = f;
    uint u = v.u;
    return (ushort)((u + 0x7fffu + ((u >> 16) & 1u)) >> 16);
}
__device__ __forceinline__ float bf2f(ushort s) {
    union { uint u; float f; } v; v.u = ((uint)s) << 16;
    return v.f;
}
__device__ __forceinline__ uint pk(float a, float b) {
    return (uint)f2bf(a) | ((uint)f2bf(b) << 16);
}
__device__ __forceinline__ float bflo(uint u) {
    union { uint u; float f; } v; v.u = u << 16; return v.f;
}
__device__ __forceinline__ float bfhi(uint u) {
    union { uint u; float f; } v; v.u = u & 0xffff0000u; return v.f;
}

// ---------------------------------------------------------------------------
// K1: v[b, j, px] = sum_c Wm[j,c] * x[b,c,px]   (bf16 out), via MFMA.
// [UNCHANGED — conventions here are HW-verified by 3 passing benches; k2 v5
//  reuses exactly these fragment layouts]
// ---------------------------------------------------------------------------
__global__ __launch_bounds__(256) void k1_mix(
    const float* __restrict__ x, const float* __restrict__ fw,
    ushort* __restrict__ v)
{
    __shared__ ushort lxs[256 * 64];   // 32 KB

    const int b      = blockIdx.x >> 8;
    const int pxbase = (blockIdx.x & 255) << 8;
    const int t      = threadIdx.x;
    const int lane   = t & 63;
    const int wv_    = t >> 6;

    {
        const int cg = lane;
        const float* xb = x + (size_t)b * C_ * HW_ + pxbase + 4 * cg;
#pragma unroll
        for (int i = 0; i < 4; ++i) {
            const int cb = wv_ * 4 + i * 16;
            const int c4 = wv_ + i * 4;
            float4 r0 = *(const float4*)(xb + (size_t)(cb + 0) * HW_);
            float4 r1 = *(const float4*)(xb + (size_t)(cb + 1) * HW_);
            float4 r2 = *(const float4*)(xb + (size_t)(cb + 2) * HW_);
            float4 r3 = *(const float4*)(xb + (size_t)(cb + 3) * HW_);
            const int sbase = c4 ^ (cg & 15);
            ushort* dst = &lxs[(4 * cg) * 64];
            *(uint2*)(dst + 0*64 + ((sbase ^ 0) * 4)) = make_uint2(pk(r0.x, r1.x), pk(r2.x, r3.x));
            *(uint2*)(dst + 1*64 + ((sbase ^ 4) * 4)) = make_uint2(pk(r0.y, r1.y), pk(r2.y, r3.y));
            *(uint2*)(dst + 2*64 + ((sbase ^ 8) * 4)) = make_uint2(pk(r0.z, r1.z), pk(r2.z, r3.z));
            *(uint2*)(dst + 3*64 + ((sbase ^ 12) * 4)) = make_uint2(pk(r0.w, r1.w), pk(r2.w, r3.w));
        }
    }

    const int n = lane & 15;
    const int q = lane >> 4;
    union Frag { short8 v; uint u[4]; };
    Frag wf[3][2];
#pragma unroll
    for (int i = 0; i < 3; ++i) {
        const int j  = (wv_ * 3 + i) * 16 + n;
        const float* wr = fw + (size_t)(j & 63) * J_ + (j >> 6) * 64;
#pragma unroll
        for (int kh = 0; kh < 2; ++kh) {
            float4 w0 = *(const float4*)(wr + kh * 32 + q * 8);
            float4 w1 = *(const float4*)(wr + kh * 32 + q * 8 + 4);
            wf[i][kh].u[0] = pk(w0.x, w0.y);
            wf[i][kh].u[1] = pk(w0.z, w0.w);
            wf[i][kh].u[2] = pk(w1.x, w1.y);
            wf[i][kh].u[3] = pk(w1.z, w1.w);
        }
    }

    __syncthreads();

    for (int mt = 0; mt < 16; ++mt) {
        const int px = mt * 16 + (lane & 15);
        const ushort* row = &lxs[px * 64];
        const int s = ((px >> 2) & 15) ^ ((px & 3) << 2);
        Frag a0, a1;
        {
            uint2 lo  = *(const uint2*)&row[((2*q    ) ^ s) * 4];
            uint2 hi  = *(const uint2*)&row[((2*q + 1) ^ s) * 4];
            a0.u[0] = lo.x;  a0.u[1] = lo.y;  a0.u[2] = hi.x;  a0.u[3] = hi.y;
            uint2 lo1 = *(const uint2*)&row[((8 + 2*q    ) ^ s) * 4];
            uint2 hi1 = *(const uint2*)&row[((8 + 2*q + 1) ^ s) * 4];
            a1.u[0] = lo1.x; a1.u[1] = lo1.y; a1.u[2] = hi1.x; a1.u[3] = hi1.y;
        }
#pragma unroll
        for (int i = 0; i < 3; ++i) {
            f32x4 acc = {0.f, 0.f, 0.f, 0.f};
            acc = __builtin_amdgcn_mfma_f32_16x16x32_bf16(a0.v, wf[i][0].v, acc, 0, 0, 0);
            acc = __builtin_amdgcn_mfma_f32_16x16x32_bf16(a1.v, wf[i][1].v, acc, 0, 0, 0);
            const int j   = (wv_ * 3 + i) * 16 + n;
            const int pxg = pxbase + mt * 16 + q * 4;
            *(uint2*)&v[(size_t)(b * J_ + j) * HW_ + pxg] =
                make_uint2(pk(acc[0], acc[1]), pk(acc[2], acc[3]));
        }
    }
}

// ---------------------------------------------------------------------------
// K2 (v5): hblur -> TRANSPOSED LDS tiles; vblur = banded MFMA, A-frag via
// plain ds_read_b128 (no tr-read — its semantics burned rounds 3+4).
//
// Per scale: 16 col-tiles, tile = [16 cols][COL_US rows] ushorts (col-major).
//   s0/s1: COL_US=24 (rows 0..23 stored; kk>=24 handled by lane mask, G=0).
//   s2:    COL_US=40 (rows 0..31 stored, 32..39 pad never read).
// A-frag: lane l reads &tile[(l&15)*COL_US + 8*(l>>4)] -> 8 consecutive
// ushorts = tmp[kk=8q+e][col=l&15] — IDENTITY with k1's verified k=8q+e
// convention. B (G band) built per-lane with the same identity mapping.
// Out[c, r] = sum_kk tmp[kk][c] * G[r][kk]; G[r][kk]=garr[kk-r], garr
// center-indexed at R. G split hi+lo bf16 -> f32-accurate vertical taps.
// hblur jobs regrouped 4-rows x 4-cols (5 jobs/thread, wave-uniform) so the
// transposed write is 4x contiguous b64.
// ---------------------------------------------------------------------------
#define COL01  24                     // ushorts per col, scales 0/1
#define TIL01  392                    // 16*24 + 8 pad (784 B, !=0 mod 128)
#define COL2   40                     // scale 2 (80 B, mult of 16 -> aligned b128)
#define TIL2   648                    // 16*40 + 8 pad (1296 B)
#define S0B    0
#define S1B    (16*TIL01)             // 6272 us
#define S2B    (2*16*TIL01)           // 12544 us
#define LDSTOT (S2B + 16*TIL2)        // 22912 us = 45824 B -> 3 blocks/CU

struct Taps {
    float g0[5];    // sigma 0.5, r=2
    float g1[7];    // sigma 1.0, r=3
    float g2[13];   // sigma 2.0, r=6
    float ke[3];    // log2(e)/(2*sigma^2)
    float cn[3];    // 1/sum (double-precision normalization, matches ref)
};

union BF8 { short8 v; uint u[4]; };

// Banded G fragment (B operand), hi/lo-compensated bf16. kk = 8q + e.
template<int R>
__device__ __forceinline__ void make_gband(float ke, float cn, int n, int q,
                                           BF8& hi, BF8& lo)
{
    float val[8];
#pragma unroll
    for (int e = 0; e < 8; ++e) {
        const int kk = 8 * q + e;                  // identity k mapping
        const int d  = kk - n;                     // tap index in [0, 2R]
        float vv = 0.f;
        if (d >= 0 && d <= 2*R) {
            const int dist = d - R;                // distance from center
            vv = exp2f(-(float)(dist*dist) * ke) * cn;
        }
        val[e] = vv;
    }
#pragma unroll
    for (int i = 0; i < 4; ++i) {
        const ushort h0 = f2bf(val[2*i]);
        const ushort h1 = f2bf(val[2*i+1]);
        hi.u[i] = (uint)h0 | ((uint)h1 << 16);
        lo.u[i] = pk(val[2*i] - bf2f(h0), val[2*i+1] - bf2f(h1));
    }
}

// hblur one 4-row x 4-col job; write transposed (4x b64, one per col).
// Rows 4qd..4qd+3; cols 4cg..4cg+3; tbase = scale base + (cg>>2)*TILE (us).
template<int R, int G, int NROWS, int CUS>
__device__ __forceinline__ void hjob4(
    const ushort* __restrict__ vplane, const float* __restrict__ g,
    ushort* __restrict__ lds, int tbase, int h0, int qd, int cg,
    const int* coff, const uint* cmsk)
{
    constexpr int NG = 2*G + 1, K = 2*R + 1, OFF = 4*G - R;
    float o[4][4];
#pragma unroll
    for (int rr = 0; rr < 4; ++rr) {
        const int r  = 4*qd + rr;
        const int gh = h0 - R + r;
        const int ghc = gh < 0 ? 0 : (gh > H_-1 ? H_-1 : gh);
        const float rv = (gh >= 0 && gh < H_ && r < NROWS) ? 1.f : 0.f;
        const char* vr = (const char*)(vplane + (size_t)ghc * W_);
        uint2 raw[NG];
#pragma unroll
        for (int gi = 0; gi < NG; ++gi)
            raw[gi] = *(const uint2*)(vr + coff[gi]);
        float win[NG*4];
#pragma unroll
        for (int gi = 0; gi < NG; ++gi) {
            const uint dx = raw[gi].x & cmsk[gi];
            const uint dy = raw[gi].y & cmsk[gi];
            win[gi*4+0] = bflo(dx); win[gi*4+1] = bfhi(dx);
            win[gi*4+2] = bflo(dy); win[gi*4+3] = bfhi(dy);
        }
#pragma unroll
        for (int i2 = 0; i2 < 4; ++i2) {
            float s = 0.f;
#pragma unroll
            for (int dd = 0; dd < K; ++dd) s += g[dd] * win[OFF + dd + i2];
            o[rr][i2] = s * rv;
        }
    }
    // transposed pack: col (4*(cg&3)+i2), rows 4qd..+3 contiguous
    ushort* base = lds + tbase + 4*qd;
#pragma unroll
    for (int i2 = 0; i2 < 4; ++i2) {
        *(uint2*)&base[(4*(cg&3) + i2) * CUS] =
            make_uint2(pk(o[0][i2], o[1][i2]), pk(o[2][i2], o[3][i2]));
    }
}

__global__ __launch_bounds__(256, 3) void k2_blur(
    const ushort* __restrict__ v, const float* __restrict__ x,
    const float* __restrict__ bias, float* __restrict__ out,
    Taps taps)
{
    __shared__ ushort tmp2[LDSTOT];   // 45824 B

    const int t    = blockIdx.x;
    const int tile = t & 15;
    const int o    = (t >> 4) & 63;
    const int b    = t >> 10;
    const int h0   = tile * TH2_;
    const int tid  = threadIdx.x;
    const int cg   = tid & 63;
    const int rw   = tid >> 6;

    // clamped col-granule byte offsets + validity masks (shared by rows)
    int coff1[3]; uint cm1[3];
    int coff2[5]; uint cm2[5];
#pragma unroll
    for (int gi = 0; gi < 3; ++gi) {
        const int gg = cg - 1 + gi;
        const int gc = gg < 0 ? 0 : (gg > 63 ? 63 : gg);
        coff1[gi] = gc * 8;
        cm1[gi]   = (gg == gc) ? 0xffffffffu : 0u;
    }
#pragma unroll
    for (int gi = 0; gi < 5; ++gi) {
        const int gg = cg - 2 + gi;
        const int gc = gg < 0 ? 0 : (gg > 63 ? 63 : gg);
        coff2[gi] = gc * 8;
        cm2[gi]   = (gg == gc) ? 0xffffffffu : 0u;
    }

    const ushort* vp = v + (size_t)(b * J_ + o) * HW_;
    const int tb01 = (cg >> 2) * TIL01;
    const int tb2  = (cg >> 2) * TIL2;

    // ---- phase 1: 5 jobs/thread, wave-uniform, balanced ----
    // s0: quads 0-5 (rows 0-23; 20-23 masked->0). jobs: all threads qd=rw;
    //     threads 0-127 also qd=rw+4.
    hjob4<2,1,20,COL01>(vp, taps.g0, tmp2, S0B + tb01, h0, rw,     cg, coff1, cm1);
    if (tid < 128)
        hjob4<2,1,20,COL01>(vp, taps.g0, tmp2, S0B + tb01, h0, rw + 4, cg, coff1, cm1);
    // s1: quads 0-5 (rows 0-23; 22-23 masked). threads 128-255 take qd=rw+2.
    hjob4<3,1,22,COL01>(vp + (size_t)C_ * HW_, taps.g1, tmp2, S1B + tb01, h0, rw,     cg, coff1, cm1);
    if (tid >= 128)
        hjob4<3,1,22,COL01>(vp + (size_t)C_ * HW_, taps.g1, tmp2, S1B + tb01, h0, rw + 2, cg, coff1, cm1);
    // s2: quads 0-7 (rows 0-31; 28-31 masked). all threads qd=rw and rw+4.
    hjob4<6,2,28,COL2>(vp + (size_t)(2*C_) * HW_, taps.g2, tmp2, S2B + tb2, h0, rw,     cg, coff2, cm2);
    hjob4<6,2,28,COL2>(vp + (size_t)(2*C_) * HW_, taps.g2, tmp2, S2B + tb2, h0, rw + 4, cg, coff2, cm2);

    // ---- banded-G fragments (constant per lane) ----
    const int lane = tid & 63;
    const int n2 = lane & 15;          // B-frag n = out-row within tile
    const int q2 = lane >> 4;          // quad: k group (kk = 8*q2 + e)
    BF8 g0h, g0l, g1h, g1l, g2h, g2l;
    make_gband<2>(taps.ke[0], taps.cn[0], n2, q2, g0h, g0l);
    make_gband<3>(taps.ke[1], taps.cn[1], n2, q2, g1h, g1l);
    make_gband<6>(taps.ke[2], taps.cn[2], n2, q2, g2h, g2l);

    __syncthreads();

    // ---- phase 2: per wave 4 col-tiles; 3 b128 reads + 6 MFMAs each ----
    const uint zm = (q2 == 3) ? 0u : 0xffffffffu;   // s0/s1: kk>=24 -> 0
    const int qs = (q2 == 3) ? 0 : q2;              // safe addr for masked lanes
    const float bo = bias[o];
    const size_t obase = ((size_t)b * C_ + o) * HW_;

#pragma unroll
    for (int i = 0; i < 4; ++i) {
        const int mt = rw * 4 + i;
        // A-frags: lane reads col n2... (A m-index = lane&15 = n2 var reused)
        uint4 d0 = *(const uint4*)&tmp2[S0B + mt*TIL01 + n2*COL01 + 8*qs];
        uint4 d1 = *(const uint4*)&tmp2[S1B + mt*TIL01 + n2*COL01 + 8*qs];
        uint4 d2 = *(const uint4*)&tmp2[S2B + mt*TIL2  + n2*COL2  + 8*q2];
        d0.x &= zm; d0.y &= zm; d0.z &= zm; d0.w &= zm;
        d1.x &= zm; d1.y &= zm; d1.z &= zm; d1.w &= zm;

        BF8 a0, a1, a2;
        a0.u[0] = d0.x; a0.u[1] = d0.y; a0.u[2] = d0.z; a0.u[3] = d0.w;
        a1.u[0] = d1.x; a1.u[1] = d1.y; a1.u[2] = d1.z; a1.u[3] = d1.w;
        a2.u[0] = d2.x; a2.u[1] = d2.y; a2.u[2] = d2.z; a2.u[3] = d2.w;

        f32x4 acc = {0.f, 0.f, 0.f, 0.f};
        acc = __builtin_amdgcn_mfma_f32_16x16x32_bf16(a0.v, g0h.v, acc, 0, 0, 0);
        acc = __builtin_amdgcn_mfma_f32_16x16x32_bf16(a0.v, g0l.v, acc, 0, 0, 0);
        acc = __builtin_amdgcn_mfma_f32_16x16x32_bf16(a1.v, g1h.v, acc, 0, 0, 0);
        acc = __builtin_amdgcn_mfma_f32_16x16x32_bf16(a1.v, g1l.v, acc, 0, 0, 0);
        acc = __builtin_amdgcn_mfma_f32_16x16x32_bf16(a2.v, g2h.v, acc, 0, 0, 0);
        acc = __builtin_amdgcn_mfma_f32_16x16x32_bf16(a2.v, g2l.v, acc, 0, 0, 0);

        // D: col(lane&15)=out-row n2, row(q2*4+reg)=pixel-col -> float4
        const int orow = h0 + n2;
        const int ocol = mt * 16 + 4 * q2;
        const float* xp = x + obase + (size_t)orow * W_ + ocol;
        float4 xv = *(const float4*)xp;
        float4 rr;
        rr.x = xv.x + bo + acc[0];
        rr.y = xv.y + bo + acc[1];
        rr.z = xv.z + bo + acc[2];
        rr.w = xv.w + bo + acc[3];
        *(float4*)(out + obase + (size_t)orow * W_ + ocol) = rr;
    }
}

// ---------------------------------------------------------------------------
static void make_taps(Taps& t)
{
    auto fill = [](float* g, int k, double sigma, float* ke, float* cn) {
        int r = k / 2;
        double s = 0.0;
        for (int i = 0; i < k; ++i) {
            double w = exp(-(double)((i - r) * (i - r)) / (2.0 * sigma * sigma));
            g[i] = (float)w;
            s += w;
        }
        for (int i = 0; i < k; ++i) g[i] = (float)((double)g[i] / s);
        *ke = (float)(1.4426950408889634 / (2.0 * sigma * sigma));
        *cn = (float)(1.0 / s);
    };
    fill(t.g0, 5,  0.5, &t.ke[0], &t.cn[0]);
    fill(t.g1, 7,  1.0, &t.ke[1], &t.cn[1]);
    fill(t.g2, 13, 2.0, &t.ke[2], &t.cn[2]);
}

extern "C" void kernel_launch(void* const* d_in, const int* in_sizes, int n_in,
                              void* d_out, int out_size, void* d_ws, size_t ws_size,
                              hipStream_t stream)
{
    const float* x  = (const float*)d_in[0];
    const float* fw = (const float*)d_in[1];
    const float* fb = (const float*)d_in[2];
    float* out = (float*)d_out;
    ushort* v = (ushort*)d_ws;   // bf16 intermediate, 8*192*65536*2 = 201 MB

    Taps taps;
    make_taps(taps);

    k1_mix<<<dim3(B_ * (HW_ / 256)), dim3(256), 0, stream>>>(x, fw, v);
    k2_blur<<<dim3(B_ * C_ * (H_ / TH2_)), dim3(256), 0, stream>>>(v, x, fb, out, taps);
}